// Round 1
// 387.662 us; speedup vs baseline: 1.0861x; 1.0861x over previous
//
#include <hip/hip_runtime.h>
#include <cstdint>
#include <cstddef>

// ---------- types ----------
typedef __bf16 bf16x8 __attribute__((ext_vector_type(8)));
typedef __bf16 bf16x4 __attribute__((ext_vector_type(4)));
typedef float  f32x4  __attribute__((ext_vector_type(4)));

// async global->LDS, 16B per lane, dest = wave-uniform base + lane*16
__device__ __forceinline__ void gload_lds16(const void* g, void* l) {
    __builtin_amdgcn_global_load_lds(
        (const __attribute__((address_space(1))) void*)g,
        (__attribute__((address_space(3))) void*)l, 16, 0, 0);
}

// fused "wait + barrier": counted vmcnt keeps next tile's loads in flight.
// lgkmcnt(0) before s_barrier retires this wave's ds_reads of the previous
// tile so the buffer being re-staged (2 tiles ahead) is WAR-safe.
#define WAITB4 asm volatile("s_waitcnt vmcnt(4) lgkmcnt(0)\ns_barrier" ::: "memory")
#define WAITB0 asm volatile("s_waitcnt vmcnt(0) lgkmcnt(0)\ns_barrier" ::: "memory")

// ---------- problem constants ----------
// B=2, S=2048, Hdim=2048, NH=16, KV=4, D=128
#define SEQ 2048
#define NH 16
#define NKV 4
#define HD 128

// ---------- fused f32 -> bf16 convert of all 5 inputs (one launch) ----------
__global__ __launch_bounds__(256) void cvt_all(const float* __restrict__ hs,
                                               const float* __restrict__ wq,
                                               const float* __restrict__ wk,
                                               const float* __restrict__ wv,
                                               const float* __restrict__ wo,
                                               __bf16* __restrict__ hB,
                                               __bf16* __restrict__ WqkB,
                                               __bf16* __restrict__ WvB,
                                               __bf16* __restrict__ WoB) {
    int bid = blockIdx.x;
    const float* in; __bf16* out; int base;
    if (bid < 8192)        { in = hs; out = hB;                   base = bid; }
    else if (bid < 12288)  { in = wq; out = WqkB;                 base = bid - 8192; }
    else if (bid < 13312)  { in = wk; out = WqkB + 2048 * 2048;   base = bid - 12288; }
    else if (bid < 14336)  { in = wv; out = WvB;                  base = bid - 13312; }
    else                   { in = wo; out = WoB;                  base = bid - 14336; }
    int i = base * 256 + threadIdx.x;
    float4 v = ((const float4*)in)[i];
    bf16x4 o = { (__bf16)v.x, (__bf16)v.y, (__bf16)v.z, (__bf16)v.w };
    ((bf16x4*)out)[i] = o;
}

// ---------- shared 256x256 / BK=32 / 3-deep-ring GEMM core ----------
// LDS ring: 3 buffers x 32 KB. Buffer = A-tile [4 slab][256 row][8 elem]
// (16 KB, conflict-free: 16-lane groups read 256 B contiguous) then B-tile.
// Stage one K-tile: 16 A-chunks + 16 B-chunks of 1 KB; wave w -> chunks 2w,2w+1.
// Per-thread FIFO: exactly 4 gloads per tile -> vmcnt(4) at boundaries proves
// tile t landed while tile t+1's 4 loads stay in flight (never vmcnt(0) in loop).
__device__ __forceinline__ void stage256(const __bf16* __restrict__ Amat,
                                         const __bf16* __restrict__ Bmat,
                                         char* ldsbuf, int bm, int bn, int k0,
                                         int wave, int lane) {
#pragma unroll
    for (int tt = 0; tt < 2; ++tt) {
        int c = wave * 2 + tt;                 // chunk 0..15
        int row = ((c & 3) << 6) + lane;       // row in 256-tile
        int ko = (c >> 2) << 3;                // k-slab * 8 elems
        gload_lds16(Amat + (size_t)(bm + row) * 2048 + k0 + ko, ldsbuf + c * 1024);
        gload_lds16(Bmat + (size_t)(bn + row) * 2048 + k0 + ko, ldsbuf + 16384 + c * 1024);
    }
}

// one K-tile of MFMA: 8 A-frags x 4 B-frags -> 32 MFMA, 12 ds_read_b128
__device__ __forceinline__ void mfma_tile256(const char* buf, int quad, int l16,
                                             int wr128, int colbase,
                                             f32x4 acc[8][4]) {
    const __bf16* bA = (const __bf16*)buf;
    const __bf16* bB = bA + 8192;
    bf16x8 af[8], bq[4];
#pragma unroll
    for (int i = 0; i < 8; ++i)
        af[i] = *(const bf16x8*)(bA + quad * 2048 + (wr128 + i * 16 + l16) * 8);
#pragma unroll
    for (int j = 0; j < 4; ++j)
        bq[j] = *(const bf16x8*)(bB + quad * 2048 +
                                 (colbase + (j & 1) * 16 + (j >> 1) * 64 + l16) * 8);
    __builtin_amdgcn_s_setprio(1);
#pragma unroll
    for (int i = 0; i < 8; ++i)
#pragma unroll
        for (int j = 0; j < 4; ++j)
            acc[i][j] = __builtin_amdgcn_mfma_f32_16x16x32_bf16(
                af[i], bq[j], acc[i][j], 0, 0, 0);
    __builtin_amdgcn_s_setprio(0);
}

// ---------- fused QKV projection GEMM, 256^2 tile, grid (16, 12) ----------
// y in [0,8):   C = hB @ Wq^T (heads 2y,2y+1) -> RoPE(+scale) -> Qr [B,NH,S,D]
// y in {8,9}:   C = hB @ Wk^T                 -> RoPE         -> Kr [B,KV,S,D]
// y in {10,11}: C = Wv_rows @ hB^T            -> plain        -> VT [KV*D][B*S]
// Wave (wr,wc): rows wr*128+[0,128), cols (wc>>1)*128 + (wc&1)*32 + {0..31,64..95}
// (keeps RoPE pairs d / d+64 in-register: acc[i][j] vs acc[i][j+2]).
__global__ __launch_bounds__(512, 2) void qkv_gemm(const __bf16* __restrict__ hB,
                                                   const __bf16* __restrict__ Wqk,
                                                   const __bf16* __restrict__ Wv,
                                                   __bf16* __restrict__ Qr,
                                                   __bf16* __restrict__ Kr,
                                                   __bf16* __restrict__ VT) {
    __shared__ __align__(16) char lds[3 * 32768];   // 96 KB ring
    const int tid = threadIdx.x;
    const int wave = tid >> 6, lane = tid & 63;
    const int quad = lane >> 4, l16 = lane & 15;
    const int wr = wave >> 2, wc = wave & 3;
    const int x = blockIdx.x, y = blockIdx.y;
    const bool isVT = (y >= 10);
    const bool isQ = (y < 8);

    const __bf16* Amat = isVT ? Wv : hB;
    const __bf16* Bmat = isVT ? hB : (isQ ? Wqk : Wqk + 2048 * 2048);
    const int bm = isVT ? (y - 10) * 256 : x * 256;
    const int bn = isVT ? x * 256 : (isQ ? y * 256 : (y - 8) * 256);

    const int wr128 = wr * 128;
    const int colbase = (wc >> 1) * 128 + (wc & 1) * 32;

    f32x4 acc[8][4] = {};

    // prologue: tiles 0,1 -> buffers 0,1 (8 loads in flight per thread)
    stage256(Amat, Bmat, lds, bm, bn, 0, wave, lane);
    stage256(Amat, Bmat, lds + 32768, bm, bn, 32, wave, lane);

    int cb = 0;
    for (int t = 0; t < 63; ++t) {
        WAITB4;                                   // tile t landed; t+1 in flight
        if (t < 62) {
            int sb = cb + 2; if (sb >= 3) sb -= 3;
            stage256(Amat, Bmat, lds + sb * 32768, bm, bn, (t + 2) * 32, wave, lane);
        }
        mfma_tile256(lds + cb * 32768, quad, l16, wr128, colbase, acc);
        if (++cb == 3) cb = 0;
    }
    WAITB0;                                       // final tile: drain
    mfma_tile256(lds + cb * 32768, quad, l16, wr128, colbase, acc);

    if (isVT) {
#pragma unroll
        for (int i = 0; i < 8; ++i)
#pragma unroll
            for (int j = 0; j < 4; ++j) {
                int row = bm + wr128 + i * 16 + quad * 4;
                int col = bn + colbase + (j & 1) * 16 + (j >> 1) * 64 + l16;
#pragma unroll
                for (int r = 0; r < 4; ++r)
                    VT[(size_t)(row + r) * 4096 + col] = (__bf16)acc[i][j][r];
            }
    } else {
        __bf16* outp = isQ ? Qr : Kr;
        const float sc = isQ ? 0.08838834764831845f : 1.0f;  // folded 1/sqrt(D)
        const int nh = isQ ? NH : NKV;
        const int hh = (isQ ? y * 2 : (y - 8) * 2) + (wc >> 1);
#pragma unroll
        for (int j2 = 0; j2 < 2; ++j2) {
            int d = (wc & 1) * 32 + j2 * 16 + l16;              // 0..63
            float inv = exp2f(-(float)d * 0.2076205059304601f); // log2(1e4)/64
#pragma unroll
            for (int i = 0; i < 8; ++i)
#pragma unroll
                for (int r = 0; r < 4; ++r) {
                    int m = bm + wr128 + i * 16 + quad * 4 + r;
                    int s = m & (SEQ - 1), b = m >> 11;
                    float f = (float)s * inv;
                    float c = __cosf(f) * sc, sn = __sinf(f) * sc;
                    float x1 = acc[i][j2][r], x2 = acc[i][j2 + 2][r];
                    size_t rb = ((size_t)(b * nh + hh) * SEQ + s) * HD;
                    outp[rb + d]      = (__bf16)(x1 * c - x2 * sn);
                    outp[rb + d + 64] = (__bf16)(x2 * c + x1 * sn);
                }
        }
    }
}

// ---------- B^T GEMM (Wo projection), 256^2 tile, f32 out, grid (16, 8) ----------
__global__ __launch_bounds__(512, 2) void gemm_bt_f32(const __bf16* __restrict__ A,
                                                      const __bf16* __restrict__ W,
                                                      float* __restrict__ C) {
    __shared__ __align__(16) char lds[3 * 32768];
    const int tid = threadIdx.x;
    const int wave = tid >> 6, lane = tid & 63;
    const int quad = lane >> 4, l16 = lane & 15;
    const int wr = wave >> 2, wc = wave & 3;
    const int bm = blockIdx.x * 256, bn = blockIdx.y * 256;
    const int wr128 = wr * 128;
    const int colbase = (wc >> 1) * 128 + (wc & 1) * 32;

    f32x4 acc[8][4] = {};

    stage256(A, W, lds, bm, bn, 0, wave, lane);
    stage256(A, W, lds + 32768, bm, bn, 32, wave, lane);

    int cb = 0;
    for (int t = 0; t < 63; ++t) {
        WAITB4;
        if (t < 62) {
            int sb = cb + 2; if (sb >= 3) sb -= 3;
            stage256(A, W, lds + sb * 32768, bm, bn, (t + 2) * 32, wave, lane);
        }
        mfma_tile256(lds + cb * 32768, quad, l16, wr128, colbase, acc);
        if (++cb == 3) cb = 0;
    }
    WAITB0;
    mfma_tile256(lds + cb * 32768, quad, l16, wr128, colbase, acc);

#pragma unroll
    for (int i = 0; i < 8; ++i)
#pragma unroll
        for (int j = 0; j < 4; ++j) {
            int row = bm + wr128 + i * 16 + quad * 4;
            int col = bn + colbase + (j & 1) * 16 + (j >> 1) * 64 + l16;
#pragma unroll
            for (int r = 0; r < 4; ++r)
                C[(size_t)(row + r) * 2048 + col] = acc[i][j][r];
        }
}

// ---------- flash attention, split-K x2, 32 q/wave (unchanged) ----------
__global__ __launch_bounds__(256) void attn_kernel(const __bf16* __restrict__ Q,
                                                   const __bf16* __restrict__ Kr,
                                                   const __bf16* __restrict__ VT,
                                                   __bf16* __restrict__ AOp0,
                                                   __bf16* __restrict__ AOp1,
                                                   float* __restrict__ lsum) {
    __shared__ __align__(16) __bf16 kt[16][64][8];  // [d-slab][kpos][8]
    __shared__ __align__(16) __bf16 vt[8][128][8];  // [kpos-slab][d][8]
    __shared__ __align__(16) __bf16 Pb[4][32][72];  // [wave][q][kpos + pad8]

    const int tid = threadIdx.x;
    const int wave = tid >> 6, lane = tid & 63;
    const int quad = lane >> 4, l16 = lane & 15;
    const int h = blockIdx.y, z = blockIdx.z;
    const int b = z >> 1, ks = z & 1, kv = h >> 2;
    const int qbase = blockIdx.x * 128 + wave * 32;

    bf16x8 qf[2][4];
#pragma unroll
    for (int qs = 0; qs < 2; ++qs) {
        const __bf16* Qp =
            Q + ((size_t)(b * NH + h) * SEQ + qbase + qs * 16 + l16) * HD + quad * 8;
#pragma unroll
        for (int kq = 0; kq < 4; ++kq) qf[qs][kq] = *(const bf16x8*)(Qp + kq * 32);
    }

    const __bf16* Kp = Kr + (size_t)(b * NKV + kv) * SEQ * HD;
    const __bf16* Vp = VT + (size_t)(kv * HD) * (2 * SEQ) + b * SEQ;

    f32x4 oacc[2][8] = {};
    float lpart[2] = {0.f, 0.f};

    for (int k0 = ks * 1024; k0 < ks * 1024 + 1024; k0 += 64) {
        __syncthreads();
#pragma unroll
        for (int t = 0; t < 4; ++t) {
            int c = wave * 4 + t;
            gload_lds16(Kp + (size_t)(k0 + lane) * HD + c * 8,
                        (char*)&kt[0][0][0] + c * 1024);
            gload_lds16(Vp + (size_t)(((c & 1) << 6) + lane) * (2 * SEQ) + k0 + (c >> 1) * 8,
                        (char*)&vt[0][0][0] + c * 1024);
        }
        __syncthreads();

        // S^T tile: ka shared by both q-sets (2 MFMA per ds_read)
#pragma unroll
        for (int mt = 0; mt < 4; ++mt) {
            f32x4 s0 = {0.f, 0.f, 0.f, 0.f}, s1 = {0.f, 0.f, 0.f, 0.f};
#pragma unroll
            for (int kq = 0; kq < 4; ++kq) {
                bf16x8 ka = *(const bf16x8*)&kt[kq * 4 + quad][mt * 16 + l16][0];
                s0 = __builtin_amdgcn_mfma_f32_16x16x32_bf16(ka, qf[0][kq], s0, 0, 0, 0);
                s1 = __builtin_amdgcn_mfma_f32_16x16x32_bf16(ka, qf[1][kq], s1, 0, 0, 0);
            }
            bf16x4 pk0, pk1;
#pragma unroll
            for (int r = 0; r < 4; ++r) {
                float p0 = __expf(s0[r]);
                float p1 = __expf(s1[r]);
                lpart[0] += p0; lpart[1] += p1;
                pk0[r] = (__bf16)p0; pk1[r] = (__bf16)p1;
            }
            *(bf16x4*)&Pb[wave][l16][mt * 16 + quad * 4] = pk0;
            *(bf16x4*)&Pb[wave][16 + l16][mt * 16 + quad * 4] = pk1;
        }

        // O^T += VT_tile @ P^T; va shared by both q-sets
#pragma unroll
        for (int kk = 0; kk < 2; ++kk) {
            bf16x8 pb0 = *(const bf16x8*)&Pb[wave][l16][kk * 32 + quad * 8];
            bf16x8 pb1 = *(const bf16x8*)&Pb[wave][16 + l16][kk * 32 + quad * 8];
#pragma unroll
            for (int mt = 0; mt < 8; ++mt) {
                bf16x8 va = *(const bf16x8*)&vt[kk * 4 + quad][mt * 16 + l16][0];
                oacc[0][mt] = __builtin_amdgcn_mfma_f32_16x16x32_bf16(
                    va, pb0, oacc[0][mt], 0, 0, 0);
                oacc[1][mt] = __builtin_amdgcn_mfma_f32_16x16x32_bf16(
                    va, pb1, oacc[1][mt], 0, 0, 0);
            }
        }
    }

    // epilogue: unnormalized partial O^T (bf16) + l partials (f32)
    __bf16* AOp = ks ? AOp1 : AOp0;
#pragma unroll
    for (int qs = 0; qs < 2; ++qs) {
        lpart[qs] += __shfl_xor(lpart[qs], 16);
        lpart[qs] += __shfl_xor(lpart[qs], 32);
        int q = qbase + qs * 16 + l16;
#pragma unroll
        for (int mt = 0; mt < 8; ++mt) {
            bf16x4 ov;
#pragma unroll
            for (int r = 0; r < 4; ++r) ov[r] = (__bf16)oacc[qs][mt][r];
            *(bf16x4*)(AOp + ((size_t)(b * SEQ + q)) * (NH * HD) + h * HD +
                       mt * 16 + quad * 4) = ov;
        }
        if (quad == 0)
            lsum[((size_t)(ks * 2 + b) * NH + h) * SEQ + q] = lpart[qs];
    }
}

// ---------- combine split-K partials: AO = (AOp0 + AOp1) / (l0 + l1) ----------
__global__ __launch_bounds__(256) void combine_kernel(const __bf16* __restrict__ AOp0,
                                                      const __bf16* __restrict__ AOp1,
                                                      const float* __restrict__ lsum,
                                                      __bf16* __restrict__ AO) {
    int i = blockIdx.x * 256 + threadIdx.x;  // 1,048,576 threads, 8 elems each
    int row = i >> 8;                        // (b*2048+q), 0..4095
    int colIdx = i & 255;                    // *8 = col in [0,2048)
    int b = row >> 11, q = row & 2047, hh = colIdx >> 4;
    float l0 = lsum[((size_t)b * NH + hh) * SEQ + q];
    float l1 = lsum[((size_t)(2 + b) * NH + hh) * SEQ + q];
    float inv = 1.f / (l0 + l1);
    bf16x8 a0 = ((const bf16x8*)AOp0)[i];
    bf16x8 a1 = ((const bf16x8*)AOp1)[i];
    bf16x8 o;
#pragma unroll
    for (int j = 0; j < 8; ++j) o[j] = (__bf16)(((float)a0[j] + (float)a1[j]) * inv);
    ((bf16x8*)AO)[i] = o;
}

// ---------- launch ----------
extern "C" void kernel_launch(void* const* d_in, const int* in_sizes, int n_in,
                              void* d_out, int out_size, void* d_ws, size_t ws_size,
                              hipStream_t stream) {
    const float* hs = (const float*)d_in[0];
    const float* Wq = (const float*)d_in[1];
    const float* Wk = (const float*)d_in[2];
    const float* Wv = (const float*)d_in[3];
    const float* Wo = (const float*)d_in[4];
    float* out = (float*)d_out;
    char* ws = (char*)d_ws;

    // workspace layout (bytes), total 67.63 MB:
    //   Qr   [0,      16.78M)  [B][NH][S][D]     -> AO alias after attn
    //   Kr   [16.78M, 20.97M)  [B][KV][S][D]
    //   VT   [20.97M, 25.17M)  [KV*D][B*S]
    //   WoB  [25.17M, 33.56M)  [2048][2048]
    //   hB   [33.56M, 50.33M)  (dead after qkv)  -> AOp0 alias
    //   WqkB [50.33M, 60.82M)  (dead after qkv)  -> AOp1 alias [50.33M,67.11M)
    //   WvB  [60.82M, 62.91M)  (dead after qkv, inside AOp1 region)
    //   lsum [67.11M, 67.63M)  f32 [2ks][B][NH][S]
    __bf16* Qr   = (__bf16*)(ws + 0);
    __bf16* Kr   = (__bf16*)(ws + 16777216);
    __bf16* VT   = (__bf16*)(ws + 20971520);
    __bf16* WoB  = (__bf16*)(ws + 25165824);
    __bf16* hB   = (__bf16*)(ws + 33554432);
    __bf16* WqkB = (__bf16*)(ws + 50331648);
    __bf16* WvB  = (__bf16*)(ws + 60817408);
    __bf16* AOp0 = (__bf16*)(ws + 33554432);  // alias hB
    __bf16* AOp1 = (__bf16*)(ws + 50331648);  // alias WqkB+WvB
    float*  lsum = (float*) (ws + 67108864);
    __bf16* AO   = (__bf16*)(ws + 0);         // alias Qr

    // 1) one fused convert launch
    cvt_all<<<18432, 256, 0, stream>>>(hs, Wq, Wk, Wv, Wo, hB, WqkB, WvB, WoB);

    // 2) fused Q/K/V projection + RoPE + transposes (256^2, 3-ring, counted vmcnt)
    qkv_gemm<<<dim3(16, 12), 512, 0, stream>>>(hB, WqkB, WvB, Qr, Kr, VT);

    // 3) attention (split-K x2: z = b*2 + ks)
    attn_kernel<<<dim3(16, 16, 4), 256, 0, stream>>>(Qr, Kr, VT, AOp0, AOp1, lsum);

    // 4) combine partials
    combine_kernel<<<4096, 256, 0, stream>>>(AOp0, AOp1, lsum, AO);

    // 5) output projection (256^2, 3-ring, f32 out)
    gemm_bt_f32<<<dim3(16, 8), 512, 0, stream>>>(AO, WoB, out);
}

// Round 2
// 364.996 us; speedup vs baseline: 1.1535x; 1.0621x over previous
//
#include <hip/hip_runtime.h>
#include <cstdint>
#include <cstddef>

// ---------- types ----------
typedef __bf16 bf16x8 __attribute__((ext_vector_type(8)));
typedef __bf16 bf16x4 __attribute__((ext_vector_type(4)));
typedef float  f32x4  __attribute__((ext_vector_type(4)));

// async global->LDS, 16B per lane, dest = wave-uniform base + lane*16
__device__ __forceinline__ void gload_lds16(const void* g, void* l) {
    __builtin_amdgcn_global_load_lds(
        (const __attribute__((address_space(1))) void*)g,
        (__attribute__((address_space(3))) void*)l, 16, 0, 0);
}

// fused "wait + barrier": counted vmcnt keeps next tile's loads in flight.
// lgkmcnt(0) before s_barrier retires this wave's ds_reads of the previous
// tile so the buffer being re-staged (2 tiles ahead) is WAR-safe.
#define WAITB4 asm volatile("s_waitcnt vmcnt(4) lgkmcnt(0)\ns_barrier" ::: "memory")
#define WAITB0 asm volatile("s_waitcnt vmcnt(0) lgkmcnt(0)\ns_barrier" ::: "memory")

// ---------- problem constants ----------
// B=2, S=2048, Hdim=2048, NH=16, KV=4, D=128
#define SEQ 2048
#define NH 16
#define NKV 4
#define HD 128

// ---------- fused f32 -> bf16 convert of all 5 inputs (one launch) ----------
__global__ __launch_bounds__(256) void cvt_all(const float* __restrict__ hs,
                                               const float* __restrict__ wq,
                                               const float* __restrict__ wk,
                                               const float* __restrict__ wv,
                                               const float* __restrict__ wo,
                                               __bf16* __restrict__ hB,
                                               __bf16* __restrict__ WqkB,
                                               __bf16* __restrict__ WvB,
                                               __bf16* __restrict__ WoB) {
    int bid = blockIdx.x;
    const float* in; __bf16* out; int base;
    if (bid < 8192)        { in = hs; out = hB;                   base = bid; }
    else if (bid < 12288)  { in = wq; out = WqkB;                 base = bid - 8192; }
    else if (bid < 13312)  { in = wk; out = WqkB + 2048 * 2048;   base = bid - 12288; }
    else if (bid < 14336)  { in = wv; out = WvB;                  base = bid - 13312; }
    else                   { in = wo; out = WoB;                  base = bid - 14336; }
    int i = base * 256 + threadIdx.x;
    float4 v = ((const float4*)in)[i];
    bf16x4 o = { (__bf16)v.x, (__bf16)v.y, (__bf16)v.z, (__bf16)v.w };
    ((bf16x4*)out)[i] = o;
}

// ---------- shared 256x256 / BK=32 / 3-deep-ring GEMM core ----------
__device__ __forceinline__ void stage256(const __bf16* __restrict__ Amat,
                                         const __bf16* __restrict__ Bmat,
                                         char* ldsbuf, int bm, int bn, int k0,
                                         int wave, int lane) {
#pragma unroll
    for (int tt = 0; tt < 2; ++tt) {
        int c = wave * 2 + tt;                 // chunk 0..15
        int row = ((c & 3) << 6) + lane;       // row in 256-tile
        int ko = (c >> 2) << 3;                // k-slab * 8 elems
        gload_lds16(Amat + (size_t)(bm + row) * 2048 + k0 + ko, ldsbuf + c * 1024);
        gload_lds16(Bmat + (size_t)(bn + row) * 2048 + k0 + ko, ldsbuf + 16384 + c * 1024);
    }
}

// one K-tile of MFMA: 8 A-frags x 4 B-frags -> 32 MFMA, 12 ds_read_b128
__device__ __forceinline__ void mfma_tile256(const char* buf, int quad, int l16,
                                             int wr128, int colbase,
                                             f32x4 acc[8][4]) {
    const __bf16* bA = (const __bf16*)buf;
    const __bf16* bB = bA + 8192;
    bf16x8 af[8], bq[4];
#pragma unroll
    for (int i = 0; i < 8; ++i)
        af[i] = *(const bf16x8*)(bA + quad * 2048 + (wr128 + i * 16 + l16) * 8);
#pragma unroll
    for (int j = 0; j < 4; ++j)
        bq[j] = *(const bf16x8*)(bB + quad * 2048 +
                                 (colbase + (j & 1) * 16 + (j >> 1) * 64 + l16) * 8);
    __builtin_amdgcn_s_setprio(1);
#pragma unroll
    for (int i = 0; i < 8; ++i)
#pragma unroll
        for (int j = 0; j < 4; ++j)
            acc[i][j] = __builtin_amdgcn_mfma_f32_16x16x32_bf16(
                af[i], bq[j], acc[i][j], 0, 0, 0);
    __builtin_amdgcn_s_setprio(0);
}

// ---------- fused QKV projection GEMM, 256^2 tile, grid (16, 12) ----------
__global__ __launch_bounds__(512, 2) void qkv_gemm(const __bf16* __restrict__ hB,
                                                   const __bf16* __restrict__ Wqk,
                                                   const __bf16* __restrict__ Wv,
                                                   __bf16* __restrict__ Qr,
                                                   __bf16* __restrict__ Kr,
                                                   __bf16* __restrict__ VT) {
    __shared__ __align__(16) char lds[3 * 32768];   // 96 KB ring
    const int tid = threadIdx.x;
    const int wave = tid >> 6, lane = tid & 63;
    const int quad = lane >> 4, l16 = lane & 15;
    const int wr = wave >> 2, wc = wave & 3;
    const int x = blockIdx.x, y = blockIdx.y;
    const bool isVT = (y >= 10);
    const bool isQ = (y < 8);

    const __bf16* Amat = isVT ? Wv : hB;
    const __bf16* Bmat = isVT ? hB : (isQ ? Wqk : Wqk + 2048 * 2048);
    const int bm = isVT ? (y - 10) * 256 : x * 256;
    const int bn = isVT ? x * 256 : (isQ ? y * 256 : (y - 8) * 256);

    const int wr128 = wr * 128;
    const int colbase = (wc >> 1) * 128 + (wc & 1) * 32;

    f32x4 acc[8][4] = {};

    stage256(Amat, Bmat, lds, bm, bn, 0, wave, lane);
    stage256(Amat, Bmat, lds + 32768, bm, bn, 32, wave, lane);

    int cb = 0;
    for (int t = 0; t < 63; ++t) {
        WAITB4;                                   // tile t landed; t+1 in flight
        if (t < 62) {
            int sb = cb + 2; if (sb >= 3) sb -= 3;
            stage256(Amat, Bmat, lds + sb * 32768, bm, bn, (t + 2) * 32, wave, lane);
        }
        mfma_tile256(lds + cb * 32768, quad, l16, wr128, colbase, acc);
        if (++cb == 3) cb = 0;
    }
    WAITB0;                                       // final tile: drain
    mfma_tile256(lds + cb * 32768, quad, l16, wr128, colbase, acc);

    if (isVT) {
#pragma unroll
        for (int i = 0; i < 8; ++i)
#pragma unroll
            for (int j = 0; j < 4; ++j) {
                int row = bm + wr128 + i * 16 + quad * 4;
                int col = bn + colbase + (j & 1) * 16 + (j >> 1) * 64 + l16;
#pragma unroll
                for (int r = 0; r < 4; ++r)
                    VT[(size_t)(row + r) * 4096 + col] = (__bf16)acc[i][j][r];
            }
    } else {
        __bf16* outp = isQ ? Qr : Kr;
        const float sc = isQ ? 0.08838834764831845f : 1.0f;  // folded 1/sqrt(D)
        const int nh = isQ ? NH : NKV;
        const int hh = (isQ ? y * 2 : (y - 8) * 2) + (wc >> 1);
#pragma unroll
        for (int j2 = 0; j2 < 2; ++j2) {
            int d = (wc & 1) * 32 + j2 * 16 + l16;              // 0..63
            float inv = exp2f(-(float)d * 0.2076205059304601f); // log2(1e4)/64
#pragma unroll
            for (int i = 0; i < 8; ++i)
#pragma unroll
                for (int r = 0; r < 4; ++r) {
                    int m = bm + wr128 + i * 16 + quad * 4 + r;
                    int s = m & (SEQ - 1), b = m >> 11;
                    float f = (float)s * inv;
                    float c = __cosf(f) * sc, sn = __sinf(f) * sc;
                    float x1 = acc[i][j2][r], x2 = acc[i][j2 + 2][r];
                    size_t rb = ((size_t)(b * nh + hh) * SEQ + s) * HD;
                    outp[rb + d]      = (__bf16)(x1 * c - x2 * sn);
                    outp[rb + d + 64] = (__bf16)(x2 * c + x1 * sn);
                }
        }
    }
}

// ---------- B^T GEMM (Wo projection), 256^2 tile, f32 out, grid (16, 8) ----------
__global__ __launch_bounds__(512, 2) void gemm_bt_f32(const __bf16* __restrict__ A,
                                                      const __bf16* __restrict__ W,
                                                      float* __restrict__ C) {
    __shared__ __align__(16) char lds[3 * 32768];
    const int tid = threadIdx.x;
    const int wave = tid >> 6, lane = tid & 63;
    const int quad = lane >> 4, l16 = lane & 15;
    const int wr = wave >> 2, wc = wave & 3;
    const int bm = blockIdx.x * 256, bn = blockIdx.y * 256;
    const int wr128 = wr * 128;
    const int colbase = (wc >> 1) * 128 + (wc & 1) * 32;

    f32x4 acc[8][4] = {};

    stage256(A, W, lds, bm, bn, 0, wave, lane);
    stage256(A, W, lds + 32768, bm, bn, 32, wave, lane);

    int cb = 0;
    for (int t = 0; t < 63; ++t) {
        WAITB4;
        if (t < 62) {
            int sb = cb + 2; if (sb >= 3) sb -= 3;
            stage256(A, W, lds + sb * 32768, bm, bn, (t + 2) * 32, wave, lane);
        }
        mfma_tile256(lds + cb * 32768, quad, l16, wr128, colbase, acc);
        if (++cb == 3) cb = 0;
    }
    WAITB0;
    mfma_tile256(lds + cb * 32768, quad, l16, wr128, colbase, acc);

#pragma unroll
    for (int i = 0; i < 8; ++i)
#pragma unroll
        for (int j = 0; j < 4; ++j) {
            int row = bm + wr128 + i * 16 + quad * 4;
            int col = bn + colbase + (j & 1) * 16 + (j >> 1) * 64 + l16;
#pragma unroll
            for (int r = 0; r < 4; ++r)
                C[(size_t)(row + r) * 2048 + col] = acc[i][j][r];
        }
}

// ---------- flash attention v2: 8 waves, q-tile 256, full k-range, ----------
// ---------- 3-deep LDS ring + counted vmcnt (no split-K, no combine) ----------
// grid (8, 16, 2): x = q-tile, y = head, z = batch. 256 blocks = 1/CU.
// Ring buffer (32 KB) = kt [16 slab][64 kpos][8] (16 KB) then vt [8][128][8].
// Stage = 32 chunks of 1 KB over 8 waves -> exactly 4 gloads/thread/tile
// -> WAITB4 at tile boundary: tile t landed, tile t+1 stays in flight.
__global__ __launch_bounds__(512, 1) void attn_kernel(const __bf16* __restrict__ Q,
                                                      const __bf16* __restrict__ Kr,
                                                      const __bf16* __restrict__ VT,
                                                      __bf16* __restrict__ AO) {
    __shared__ __align__(16) char ring[3 * 32768];   // 96 KB: kt+vt x3
    __shared__ __align__(16) __bf16 Pb[8][32][72];   // 36 KB: [wave][q][kpos+pad8]

    const int tid = threadIdx.x;
    const int wave = tid >> 6, lane = tid & 63;
    const int quad = lane >> 4, l16 = lane & 15;
    const int h = blockIdx.y, b = blockIdx.z;
    const int kv = h >> 2;
    const int qbase = blockIdx.x * 256 + wave * 32;

    // Q fragments in registers (scaled by 1/sqrt(D) at projection time)
    bf16x8 qf[2][4];
#pragma unroll
    for (int qs = 0; qs < 2; ++qs) {
        const __bf16* Qp =
            Q + ((size_t)(b * NH + h) * SEQ + qbase + qs * 16 + l16) * HD + quad * 8;
#pragma unroll
        for (int kq = 0; kq < 4; ++kq) qf[qs][kq] = *(const bf16x8*)(Qp + kq * 32);
    }

    const __bf16* Kp = Kr + (size_t)(b * NKV + kv) * SEQ * HD;
    const __bf16* Vp = VT + (size_t)(kv * HD) * (2 * SEQ) + b * SEQ;

    f32x4 oacc[2][8] = {};
    float lpart[2] = {0.f, 0.f};

    // stage one 64-kpos tile into ring buffer sb: 4 chunks per wave
    auto stage = [&](int sb, int k0) {
        char* dst = ring + sb * 32768;
#pragma unroll
        for (int tt = 0; tt < 4; ++tt) {
            int c = wave * 4 + tt;              // chunk 0..31
            if (c < 16) {                       // kt: all 64 kpos, d-slab c
                gload_lds16(Kp + (size_t)(k0 + lane) * HD + c * 8, dst + c * 1024);
            } else {                            // vt: d-half, kpos-slab
                int vc = c - 16;
                gload_lds16(Vp + (size_t)(((vc & 1) << 6) + lane) * (2 * SEQ) + k0 +
                                (vc >> 1) * 8,
                            dst + c * 1024);
            }
        }
    };

    // compute one 64-kpos tile from ring buffer cb
    auto compute = [&](int cb) {
        const __bf16* kt = (const __bf16*)(ring + cb * 32768);
        const __bf16* vt = kt + 8192;
        // S^T tile: ka shared by both q-sets (2 MFMA per ds_read)
#pragma unroll
        for (int mt = 0; mt < 4; ++mt) {
            f32x4 s0 = {0.f, 0.f, 0.f, 0.f}, s1 = {0.f, 0.f, 0.f, 0.f};
#pragma unroll
            for (int kq = 0; kq < 4; ++kq) {
                bf16x8 ka = *(const bf16x8*)(kt + (kq * 4 + quad) * 512 +
                                             (mt * 16 + l16) * 8);
                s0 = __builtin_amdgcn_mfma_f32_16x16x32_bf16(ka, qf[0][kq], s0, 0, 0, 0);
                s1 = __builtin_amdgcn_mfma_f32_16x16x32_bf16(ka, qf[1][kq], s1, 0, 0, 0);
            }
            bf16x4 pk0, pk1;
#pragma unroll
            for (int r = 0; r < 4; ++r) {
                float p0 = __expf(s0[r]);
                float p1 = __expf(s1[r]);
                lpart[0] += p0; lpart[1] += p1;
                pk0[r] = (__bf16)p0; pk1[r] = (__bf16)p1;
            }
            *(bf16x4*)&Pb[wave][l16][mt * 16 + quad * 4] = pk0;
            *(bf16x4*)&Pb[wave][16 + l16][mt * 16 + quad * 4] = pk1;
        }
        // O^T += VT_tile @ P^T; va shared by both q-sets
#pragma unroll
        for (int kk = 0; kk < 2; ++kk) {
            bf16x8 pb0 = *(const bf16x8*)&Pb[wave][l16][kk * 32 + quad * 8];
            bf16x8 pb1 = *(const bf16x8*)&Pb[wave][16 + l16][kk * 32 + quad * 8];
#pragma unroll
            for (int mt = 0; mt < 8; ++mt) {
                bf16x8 va = *(const bf16x8*)(vt + (kk * 4 + quad) * 1024 +
                                             (mt * 16 + l16) * 8);
                oacc[0][mt] = __builtin_amdgcn_mfma_f32_16x16x32_bf16(
                    va, pb0, oacc[0][mt], 0, 0, 0);
                oacc[1][mt] = __builtin_amdgcn_mfma_f32_16x16x32_bf16(
                    va, pb1, oacc[1][mt], 0, 0, 0);
            }
        }
    };

    // prologue: tiles 0,1 -> buffers 0,1 (8 loads in flight per thread)
    stage(0, 0);
    stage(1, 64);

    int cb = 0;
    for (int t = 0; t < 31; ++t) {
        WAITB4;                                   // tile t landed; t+1 in flight
        if (t < 30) {
            int sb = cb + 2; if (sb >= 3) sb -= 3;
            stage(sb, (t + 2) * 64);
        }
        compute(cb);
        if (++cb == 3) cb = 0;
    }
    WAITB0;                                       // final tile: drain
    compute(cb);

    // epilogue: normalize in-kernel (no split-K), write bf16 AO
#pragma unroll
    for (int qs = 0; qs < 2; ++qs) {
        lpart[qs] += __shfl_xor(lpart[qs], 16);
        lpart[qs] += __shfl_xor(lpart[qs], 32);
        float inv = 1.f / lpart[qs];
        int q = qbase + qs * 16 + l16;
#pragma unroll
        for (int mt = 0; mt < 8; ++mt) {
            bf16x4 ov;
#pragma unroll
            for (int r = 0; r < 4; ++r) ov[r] = (__bf16)(oacc[qs][mt][r] * inv);
            *(bf16x4*)(AO + ((size_t)(b * SEQ + q)) * (NH * HD) + h * HD +
                       mt * 16 + quad * 4) = ov;
        }
    }
}

// ---------- launch ----------
extern "C" void kernel_launch(void* const* d_in, const int* in_sizes, int n_in,
                              void* d_out, int out_size, void* d_ws, size_t ws_size,
                              hipStream_t stream) {
    const float* hs = (const float*)d_in[0];
    const float* Wq = (const float*)d_in[1];
    const float* Wk = (const float*)d_in[2];
    const float* Wv = (const float*)d_in[3];
    const float* Wo = (const float*)d_in[4];
    float* out = (float*)d_out;
    char* ws = (char*)d_ws;

    // workspace layout (bytes):
    //   Qr   [0,      16.78M)  [B][NH][S][D]
    //   Kr   [16.78M, 20.97M)  [B][KV][S][D]
    //   VT   [20.97M, 25.17M)  [KV*D][B*S]
    //   WoB  [25.17M, 33.56M)  [2048][2048]
    //   hB   [33.56M, 50.33M)  (dead after qkv)  -> AO alias (16.8 MB)
    //   WqkB [50.33M, 60.82M)  (dead after qkv)
    //   WvB  [60.82M, 62.91M)  (dead after qkv)
    __bf16* Qr   = (__bf16*)(ws + 0);
    __bf16* Kr   = (__bf16*)(ws + 16777216);
    __bf16* VT   = (__bf16*)(ws + 20971520);
    __bf16* WoB  = (__bf16*)(ws + 25165824);
    __bf16* hB   = (__bf16*)(ws + 33554432);
    __bf16* WqkB = (__bf16*)(ws + 50331648);
    __bf16* WvB  = (__bf16*)(ws + 60817408);
    __bf16* AO   = (__bf16*)(ws + 33554432);  // alias hB (dead after qkv)

    // 1) one fused convert launch
    cvt_all<<<18432, 256, 0, stream>>>(hs, Wq, Wk, Wv, Wo, hB, WqkB, WvB, WoB);

    // 2) fused Q/K/V projection + RoPE + transposes (256^2, 3-ring, counted vmcnt)
    qkv_gemm<<<dim3(16, 12), 512, 0, stream>>>(hB, WqkB, WvB, Qr, Kr, VT);

    // 3) attention: 8-wave, 3-ring, in-kernel normalization
    attn_kernel<<<dim3(8, 16, 2), 512, 0, stream>>>(Qr, Kr, VT, AO);

    // 4) output projection (256^2, 3-ring, f32 out)
    gemm_bt_f32<<<dim3(16, 8), 512, 0, stream>>>(AO, WoB, out);
}